// Round 1
// baseline (290.568 us; speedup 1.0000x reference)
//
#include <hip/hip_runtime.h>
#include <math.h>

#define DIM 16
#define HID 32

// One thread per row (16 contiguous fp32). Weights/biases are read with
// thread-uniform addressing so the compiler scalarizes them into SGPRs
// (s_load) -> FMA weight operand is an SGPR, xn/acc in VGPRs.
__global__ __launch_bounds__(256) void fused_ln_mlp_kernel(
    const float* __restrict__ x,
    const float* __restrict__ ln_w,
    const float* __restrict__ ln_b,
    const float* __restrict__ w1,   // [HID][DIM] row-major
    const float* __restrict__ b1,   // [HID]
    const float* __restrict__ w2,   // [DIM][HID] row-major
    const float* __restrict__ b2,   // [DIM]
    float* __restrict__ out,
    int nrows)
{
    int row = blockIdx.x * blockDim.x + threadIdx.x;
    if (row >= nrows) return;

    const float* xr = x + (size_t)row * DIM;

    float xv[DIM];
    {
        float4 t0 = *(const float4*)(xr + 0);
        float4 t1 = *(const float4*)(xr + 4);
        float4 t2 = *(const float4*)(xr + 8);
        float4 t3 = *(const float4*)(xr + 12);
        xv[0] = t0.x; xv[1] = t0.y; xv[2]  = t0.z; xv[3]  = t0.w;
        xv[4] = t1.x; xv[5] = t1.y; xv[6]  = t1.z; xv[7]  = t1.w;
        xv[8] = t2.x; xv[9] = t2.y; xv[10] = t2.z; xv[11] = t2.w;
        xv[12] = t3.x; xv[13] = t3.y; xv[14] = t3.z; xv[15] = t3.w;
    }

    // LayerNorm over the 16 elements
    float mu = 0.0f;
    #pragma unroll
    for (int i = 0; i < DIM; i++) mu += xv[i];
    mu *= (1.0f / DIM);

    float var = 0.0f;
    #pragma unroll
    for (int i = 0; i < DIM; i++) {
        float d = xv[i] - mu;
        var += d * d;
    }
    var *= (1.0f / DIM);
    float rstd = rsqrtf(var + 1e-5f);

    // a*x + c form: xhat = (x - mu) * rstd; xn = xhat * ln_w + ln_b
    float a = rstd;
    float c = -mu * rstd;
    float xn[DIM];
    #pragma unroll
    for (int i = 0; i < DIM; i++) {
        float xhat = fmaf(xv[i], a, c);
        xn[i] = fmaf(xhat, ln_w[i], ln_b[i]);
    }

    // h = W1 @ xn + b1 ; g = gelu_exact(h)
    float g[HID];
    #pragma unroll
    for (int h = 0; h < HID; h++) {
        float acc = b1[h];
        #pragma unroll
        for (int d = 0; d < DIM; d++) acc = fmaf(xn[d], w1[h * DIM + d], acc);
        // exact erf GELU (matches torch nn.GELU default)
        g[h] = 0.5f * acc * (1.0f + erff(acc * 0.70710678118654752f));
    }

    // y = W2 @ g + b2 ; out = x + y
    #pragma unroll
    for (int d = 0; d < DIM; d++) {
        float acc = b2[d];
        #pragma unroll
        for (int h = 0; h < HID; h++) acc = fmaf(g[h], w2[d * HID + h], acc);
        xv[d] += acc;
    }

    float* outr = out + (size_t)row * DIM;
    *(float4*)(outr + 0)  = make_float4(xv[0],  xv[1],  xv[2],  xv[3]);
    *(float4*)(outr + 4)  = make_float4(xv[4],  xv[5],  xv[6],  xv[7]);
    *(float4*)(outr + 8)  = make_float4(xv[8],  xv[9],  xv[10], xv[11]);
    *(float4*)(outr + 12) = make_float4(xv[12], xv[13], xv[14], xv[15]);
}

extern "C" void kernel_launch(void* const* d_in, const int* in_sizes, int n_in,
                              void* d_out, int out_size, void* d_ws, size_t ws_size,
                              hipStream_t stream) {
    const float* x    = (const float*)d_in[0];
    const float* ln_w = (const float*)d_in[1];
    const float* ln_b = (const float*)d_in[2];
    const float* w1   = (const float*)d_in[3];
    const float* b1   = (const float*)d_in[4];
    const float* w2   = (const float*)d_in[5];
    const float* b2   = (const float*)d_in[6];
    float* out = (float*)d_out;

    int nrows = in_sizes[0] / DIM;  // 32768*64 = 2,097,152
    int block = 256;
    int grid = (nrows + block - 1) / block;

    fused_ln_mlp_kernel<<<grid, block, 0, stream>>>(
        x, ln_w, ln_b, w1, b1, w2, b2, out, nrows);
}

// Round 2
// 258.324 us; speedup vs baseline: 1.1248x; 1.1248x over previous
//
#include <hip/hip_runtime.h>
#include <math.h>

#define DIM 16
#define HID 32

typedef float v2f __attribute__((ext_vector_type(2)));

// Branch-free exact-enough GELU: erf via Abramowitz-Stegun 7.1.26
// (max abs error 1.5e-7 — far below the bench's bf16 comparison floor).
// 1 v_rcp + 1 v_exp (quarter-rate) + ~9 full-rate VALU ops, no divergence.
__device__ inline float gelu_erf(float x) {
    const float kInvSqrt2 = 0.70710678118654752f;
    float z  = x * kInvSqrt2;
    float az = fabsf(z);
    float t  = __builtin_amdgcn_rcpf(fmaf(0.3275911f, az, 1.0f));
    float e  = __expf(-az * az);          // exp(-z^2), native v_exp_f32
    float p  = fmaf(t, 1.061405429f, -1.453152027f);
    p = fmaf(t, p, 1.421413741f);
    p = fmaf(t, p, -0.284496736f);
    p = fmaf(t, p, 0.254829592f);
    p = p * t;
    float erf_abs = fmaf(-p, e, 1.0f);    // erf(|z|) = 1 - p*exp(-z^2)
    float erfv = copysignf(erf_abs, z);
    return 0.5f * x * (1.0f + erfv);
}

__global__ __launch_bounds__(256) void fused_ln_mlp_kernel(
    const float* __restrict__ x,
    const float* __restrict__ ln_w,
    const float* __restrict__ ln_b,
    const float* __restrict__ w1,   // [HID][DIM] row-major
    const float* __restrict__ b1,   // [HID]
    const float* __restrict__ w2,   // [DIM][HID] row-major
    const float* __restrict__ b2,   // [DIM]
    float* __restrict__ out,
    int nrows)
{
    int row = blockIdx.x * blockDim.x + threadIdx.x;
    if (row >= nrows) return;

    const float* xr = x + (size_t)row * DIM;

    // Load row as 4x float4, view as 8x float2 for packed math.
    v2f xv2[8];
    {
        float4 t0 = *(const float4*)(xr + 0);
        float4 t1 = *(const float4*)(xr + 4);
        float4 t2 = *(const float4*)(xr + 8);
        float4 t3 = *(const float4*)(xr + 12);
        xv2[0] = (v2f){t0.x, t0.y}; xv2[1] = (v2f){t0.z, t0.w};
        xv2[2] = (v2f){t1.x, t1.y}; xv2[3] = (v2f){t1.z, t1.w};
        xv2[4] = (v2f){t2.x, t2.y}; xv2[5] = (v2f){t2.z, t2.w};
        xv2[6] = (v2f){t3.x, t3.y}; xv2[7] = (v2f){t3.z, t3.w};
    }

    // LayerNorm (packed)
    v2f s = xv2[0] + xv2[1];
    s += xv2[2] + xv2[3];
    s += xv2[4] + xv2[5];
    s += xv2[6] + xv2[7];
    float mu = (s.x + s.y) * (1.0f / DIM);

    v2f mu2 = (v2f){mu, mu};
    v2f vs = (v2f){0.0f, 0.0f};
    #pragma unroll
    for (int i = 0; i < 8; i++) {
        v2f d = xv2[i] - mu2;
        vs = __builtin_elementwise_fma(d, d, vs);
    }
    float var = (vs.x + vs.y) * (1.0f / DIM);
    float a = __builtin_amdgcn_rsqf(var + 1e-5f);
    float c = -mu * a;

    const v2f* lnw2 = (const v2f*)ln_w;
    const v2f* lnb2 = (const v2f*)ln_b;
    v2f a2 = (v2f){a, a};
    v2f c2 = (v2f){c, c};
    v2f xn2[8];
    #pragma unroll
    for (int i = 0; i < 8; i++) {
        v2f xhat = __builtin_elementwise_fma(xv2[i], a2, c2);
        xn2[i] = __builtin_elementwise_fma(xhat, lnw2[i], lnb2[i]);
    }

    // h = W1 @ xn + b1 ; g = gelu(h)   (packed fp32 FMA)
    float g[HID];
    #pragma unroll
    for (int h = 0; h < HID; h++) {
        const v2f* wr = (const v2f*)(w1 + h * DIM);  // uniform -> s_load
        v2f acc = (v2f){0.0f, 0.0f};
        #pragma unroll
        for (int j = 0; j < 8; j++) acc = __builtin_elementwise_fma(xn2[j], wr[j], acc);
        float hv = acc.x + acc.y + b1[h];
        g[h] = gelu_erf(hv);
    }

    // repack g as float2
    v2f g2[HID / 2];
    #pragma unroll
    for (int k = 0; k < HID / 2; k++) g2[k] = (v2f){g[2 * k], g[2 * k + 1]};

    // y = W2 @ g + b2 ; out = x + y
    float yv[DIM];
    #pragma unroll
    for (int d = 0; d < DIM; d++) {
        const v2f* wr = (const v2f*)(w2 + d * HID);  // uniform -> s_load
        v2f acc = (v2f){0.0f, 0.0f};
        #pragma unroll
        for (int k = 0; k < HID / 2; k++) acc = __builtin_elementwise_fma(g2[k], wr[k], acc);
        float xval = (d & 1) ? xv2[d >> 1].y : xv2[d >> 1].x;
        yv[d] = acc.x + acc.y + b2[d] + xval;
    }

    float* outr = out + (size_t)row * DIM;
    *(float4*)(outr + 0)  = make_float4(yv[0],  yv[1],  yv[2],  yv[3]);
    *(float4*)(outr + 4)  = make_float4(yv[4],  yv[5],  yv[6],  yv[7]);
    *(float4*)(outr + 8)  = make_float4(yv[8],  yv[9],  yv[10], yv[11]);
    *(float4*)(outr + 12) = make_float4(yv[12], yv[13], yv[14], yv[15]);
}

extern "C" void kernel_launch(void* const* d_in, const int* in_sizes, int n_in,
                              void* d_out, int out_size, void* d_ws, size_t ws_size,
                              hipStream_t stream) {
    const float* x    = (const float*)d_in[0];
    const float* ln_w = (const float*)d_in[1];
    const float* ln_b = (const float*)d_in[2];
    const float* w1   = (const float*)d_in[3];
    const float* b1   = (const float*)d_in[4];
    const float* w2   = (const float*)d_in[5];
    const float* b2   = (const float*)d_in[6];
    float* out = (float*)d_out;

    int nrows = in_sizes[0] / DIM;  // 2,097,152
    int block = 256;
    int grid = (nrows + block - 1) / block;

    fused_ln_mlp_kernel<<<grid, block, 0, stream>>>(
        x, ln_w, ln_b, w1, b1, w2, b2, out, nrows);
}

// Round 3
// 254.986 us; speedup vs baseline: 1.1395x; 1.0131x over previous
//
#include <hip/hip_runtime.h>
#include <math.h>

#define DIM 16
#define HID 32

typedef float  f32x4  __attribute__((ext_vector_type(4)));
typedef short  bf16x8 __attribute__((ext_vector_type(8)));
typedef float  v2f    __attribute__((ext_vector_type(2)));

#define ROW_STRIDE_B 80                    // LDS row: 32 bf16 = 64B data + 16B pad (16B-aligned)
#define LDS_PER_WAVE (64 * ROW_STRIDE_B)   // 5120 B

__device__ inline unsigned short f2bf(float f) {
    union { float f; unsigned u; } v; v.f = f;
    unsigned r = v.u + 0x7fffu + ((v.u >> 16) & 1u);   // RNE
    return (unsigned short)(r >> 16);
}
__device__ inline unsigned packbf(float lo, float hi) {
    return (unsigned)f2bf(lo) | ((unsigned)f2bf(hi) << 16);
}

// erf via Abramowitz-Stegun 7.1.26 (|err| < 1.5e-7), branch-free.
__device__ inline float gelu_erf(float x) {
    const float kInvSqrt2 = 0.70710678118654752f;
    float z  = x * kInvSqrt2;
    float az = fabsf(z);
    float t  = __builtin_amdgcn_rcpf(fmaf(0.3275911f, az, 1.0f));
    float e  = __expf(-az * az);
    float p  = fmaf(t, 1.061405429f, -1.453152027f);
    p = fmaf(t, p, 1.421413741f);
    p = fmaf(t, p, -0.284496736f);
    p = fmaf(t, p, 0.254829592f);
    p = p * t;
    float erf_abs = fmaf(-p, e, 1.0f);
    float erfv = copysignf(erf_abs, z);
    return 0.5f * x * (1.0f + erfv);
}

__global__ __launch_bounds__(256) void fused_ln_mlp_mfma(
    const float* __restrict__ x,
    const float* __restrict__ ln_w,
    const float* __restrict__ ln_b,
    const float* __restrict__ w1,   // [HID][DIM] row-major
    const float* __restrict__ b1,   // [HID]
    const float* __restrict__ w2,   // [DIM][HID] row-major
    const float* __restrict__ b2,   // [DIM]
    float* __restrict__ out,
    int nrows)
{
    __shared__ __align__(16) unsigned char lds_all[4 * LDS_PER_WAVE];  // 20 KiB / block

    const int tid  = threadIdx.x;
    const int lane = tid & 63;
    const int wave = tid >> 6;
    const int q    = lane >> 4;     // quad index 0..3
    const int c    = lane & 15;     // within-16 index

    unsigned char* nbuf = lds_all + wave * LDS_PER_WAVE;   // per-wave private slice
    const int rowbase = (blockIdx.x * 4 + wave) * 64;      // 64 rows per wave

    // ---- per-lane weight fragments (loaded once, L2/L3-cached) ----
    // W1 as B-operand of 16x16x32 (K=16 zero-padded to 32):
    //   B[k=8q+j][n=c+16t] = w1[(c+16t)*DIM + k], zero for k>=16 (q>=2)
    bf16x8 bW1[2];
    #pragma unroll
    for (int t = 0; t < 2; t++) {
        bf16x8 f = {0, 0, 0, 0, 0, 0, 0, 0};
        if (q < 2) {
            const float* wp = w1 + (c + 16 * t) * DIM + q * 8;
            #pragma unroll
            for (int j = 0; j < 8; j++)
                ((unsigned short*)&f)[j] = f2bf(wp[j]);
        }
        bW1[t] = f;
    }
    // W2 as B-operand of 16x16x32: B[k=8q+j][n=c] = w2[c*HID + k]
    bf16x8 bW2;
    {
        const float* wp = w2 + c * HID + q * 8;
        #pragma unroll
        for (int j = 0; j < 8; j++)
            ((unsigned short*)&bW2)[j] = f2bf(wp[j]);
    }
    const float b1v0 = b1[c];
    const float b1v1 = b1[c + 16];
    const float b2v  = b2[c];

    // ---- phase 1: lane=row load + LayerNorm (fp32) ----
    const float* xr = x + (size_t)(rowbase + lane) * DIM;
    v2f xv2[8];
    {
        float4 t0 = *(const float4*)(xr + 0);
        float4 t1 = *(const float4*)(xr + 4);
        float4 t2 = *(const float4*)(xr + 8);
        float4 t3 = *(const float4*)(xr + 12);
        xv2[0] = (v2f){t0.x, t0.y}; xv2[1] = (v2f){t0.z, t0.w};
        xv2[2] = (v2f){t1.x, t1.y}; xv2[3] = (v2f){t1.z, t1.w};
        xv2[4] = (v2f){t2.x, t2.y}; xv2[5] = (v2f){t2.z, t2.w};
        xv2[6] = (v2f){t3.x, t3.y}; xv2[7] = (v2f){t3.z, t3.w};
    }
    v2f s = xv2[0] + xv2[1];
    s += xv2[2] + xv2[3];
    s += xv2[4] + xv2[5];
    s += xv2[6] + xv2[7];
    float mu = (s.x + s.y) * (1.0f / DIM);
    v2f mu2 = (v2f){mu, mu};
    v2f vs = (v2f){0.0f, 0.0f};
    #pragma unroll
    for (int i = 0; i < 8; i++) {
        v2f d = xv2[i] - mu2;
        vs = __builtin_elementwise_fma(d, d, vs);
    }
    float var = (vs.x + vs.y) * (1.0f / DIM);
    float a = __builtin_amdgcn_rsqf(var + 1e-5f);
    float cc = -mu * a;

    const v2f* lnw2 = (const v2f*)ln_w;
    const v2f* lnb2 = (const v2f*)ln_b;
    v2f a2 = (v2f){a, a};
    v2f c2 = (v2f){cc, cc};
    float xn[16];
    #pragma unroll
    for (int i = 0; i < 8; i++) {
        v2f xh = __builtin_elementwise_fma(xv2[i], a2, c2);
        v2f r  = __builtin_elementwise_fma(xh, lnw2[i], lnb2[i]);
        xn[2 * i]     = r.x;
        xn[2 * i + 1] = r.y;
    }

    // write xn row as 32 bf16 (upper 16 = K-padding zeros)
    {
        int4 w0, w1v, zz;
        w0.x  = packbf(xn[0],  xn[1]);  w0.y  = packbf(xn[2],  xn[3]);
        w0.z  = packbf(xn[4],  xn[5]);  w0.w  = packbf(xn[6],  xn[7]);
        w1v.x = packbf(xn[8],  xn[9]);  w1v.y = packbf(xn[10], xn[11]);
        w1v.z = packbf(xn[12], xn[13]); w1v.w = packbf(xn[14], xn[15]);
        zz.x = zz.y = zz.z = zz.w = 0;
        int4* rowp = (int4*)(nbuf + lane * ROW_STRIDE_B);
        rowp[0] = w0; rowp[1] = w1v; rowp[2] = zz; rowp[3] = zz;
    }
    asm volatile("s_waitcnt lgkmcnt(0)" ::: "memory");   // wave-lockstep: writes visible

    // ---- W1 matmul: H[64 x 32] via 8x mfma_f32_16x16x32_bf16 ----
    f32x4 accH[4][2];
    #pragma unroll
    for (int rc = 0; rc < 4; rc++) {
        const bf16x8 afrag =
            *(const bf16x8*)(nbuf + (rc * 16 + c) * ROW_STRIDE_B + q * 16);
        f32x4 z0 = {0.f, 0.f, 0.f, 0.f};
        f32x4 z1 = {0.f, 0.f, 0.f, 0.f};
        accH[rc][0] = __builtin_amdgcn_mfma_f32_16x16x32_bf16(afrag, bW1[0], z0, 0, 0, 0);
        accH[rc][1] = __builtin_amdgcn_mfma_f32_16x16x32_bf16(afrag, bW1[1], z1, 0, 0, 0);
    }
    asm volatile("s_waitcnt lgkmcnt(0)" ::: "memory");   // A-reads drained before overwrite

    // ---- bias + GELU, write P (bf16) back to same LDS slice ----
    #pragma unroll
    for (int rc = 0; rc < 4; rc++) {
        #pragma unroll
        for (int t = 0; t < 2; t++) {
            #pragma unroll
            for (int r = 0; r < 4; r++) {
                float hv = accH[rc][t][r] + (t ? b1v1 : b1v0);
                float g  = gelu_erf(hv);
                *(unsigned short*)(nbuf + (rc * 16 + 4 * q + r) * ROW_STRIDE_B
                                        + (c + 16 * t) * 2) = f2bf(g);
            }
        }
    }
    asm volatile("s_waitcnt lgkmcnt(0)" ::: "memory");   // P writes visible

    // ---- W2 matmul: Y[64 x 16] via 4x mfma_f32_16x16x32_bf16 ----
    f32x4 accY[4];
    #pragma unroll
    for (int rc = 0; rc < 4; rc++) {
        const bf16x8 afrag =
            *(const bf16x8*)(nbuf + (rc * 16 + c) * ROW_STRIDE_B + q * 16);
        f32x4 z = {0.f, 0.f, 0.f, 0.f};
        accY[rc] = __builtin_amdgcn_mfma_f32_16x16x32_bf16(afrag, bW2, z, 0, 0, 0);
    }

    // ---- epilogue: +b2 + residual (x re-read, L1-hot), store in C-layout ----
    #pragma unroll
    for (int rc = 0; rc < 4; rc++) {
        #pragma unroll
        for (int r = 0; r < 4; r++) {
            int grow = rowbase + rc * 16 + 4 * q + r;
            float xres = x[(size_t)grow * DIM + c];
            out[(size_t)grow * DIM + c] = accY[rc][r] + b2v + xres;
        }
    }
}

extern "C" void kernel_launch(void* const* d_in, const int* in_sizes, int n_in,
                              void* d_out, int out_size, void* d_ws, size_t ws_size,
                              hipStream_t stream) {
    const float* x    = (const float*)d_in[0];
    const float* ln_w = (const float*)d_in[1];
    const float* ln_b = (const float*)d_in[2];
    const float* w1   = (const float*)d_in[3];
    const float* b1   = (const float*)d_in[4];
    const float* w2   = (const float*)d_in[5];
    const float* b2   = (const float*)d_in[6];
    float* out = (float*)d_out;

    int nrows = in_sizes[0] / DIM;            // 2,097,152
    int rows_per_block = 256;                 // 4 waves x 64 rows
    int grid = (nrows + rows_per_block - 1) / rows_per_block;

    fused_ln_mlp_mfma<<<grid, 256, 0, stream>>>(
        x, ln_w, ln_b, w1, b1, w2, b2, out, nrows);
}